// Round 1
// baseline (392.253 us; speedup 1.0000x reference)
//
#include <hip/hip_runtime.h>

// MoE-LoRA top-1 dispatch, fp32 baseline.
// Stages: pool(x) -> router MLP -> softmax/argmax/balance -> xr = x@A_sel^T -> out = xr@B_sel^T * 2
constexpr int B_ = 4, S_ = 2048, D_ = 4096, E_ = 4, R_ = 64, OUT_ = 4096;
constexpr int NMOD = 4, NREG = 3, HID_ = 128;
constexpr int RIN_ = D_ + NMOD + NREG;      // 4103
constexpr float SCALING_ = 2.0f;            // alpha/rank

// ws layout (floats)
constexpr int WS_POOL = 0;                  // B*D  (sum over S, pre-divide)
constexpr int WS_HACC = B_ * D_;            // B*HID
constexpr int WS_TOP  = WS_HACC + B_ * HID_;// B ints
constexpr int WS_XR   = 17408;              // B*S*R

__global__ void pool_kernel(const float* __restrict__ x, float* __restrict__ pool) {
    int q  = blockIdx.x * blockDim.x + threadIdx.x;   // float4 column id, 0..B*D/4
    int b  = q / (D_ / 4);
    int dq = q % (D_ / 4);
    int s0 = blockIdx.y * (S_ / 16);                  // 16 y-blocks x 128 rows
    const float4* xp = (const float4*)x + (size_t)b * S_ * (D_ / 4) + (size_t)s0 * (D_ / 4) + dq;
    float4 acc = {0.f, 0.f, 0.f, 0.f};
    for (int s = 0; s < S_ / 16; ++s) {
        float4 v = xp[(size_t)s * (D_ / 4)];
        acc.x += v.x; acc.y += v.y; acc.z += v.z; acc.w += v.w;
    }
    float* p = pool + b * D_ + dq * 4;
    atomicAdd(p + 0, acc.x); atomicAdd(p + 1, acc.y);
    atomicAdd(p + 2, acc.z); atomicAdd(p + 3, acc.w);
}

__global__ void router_h_kernel(const float* __restrict__ pool, const float* __restrict__ rel,
                                const float* __restrict__ reg, const float* __restrict__ w1,
                                float* __restrict__ hacc) {
    int b = blockIdx.x, kc = blockIdx.y, h = threadIdx.x; // 128 threads
    int k0 = kc * 257;
    int k1 = k0 + 257 < RIN_ ? k0 + 257 : RIN_;
    float acc = 0.f;
    for (int k = k0; k < k1; ++k) {
        float rin;
        if (k < D_)            rin = pool[b * D_ + k] * (1.0f / S_);
        else if (k < D_ + NMOD) rin = rel[b * NMOD + (k - D_)];
        else                    rin = reg[b * NREG + (k - D_ - NMOD)];
        acc += rin * w1[k * HID_ + h];
    }
    atomicAdd(&hacc[b * HID_ + h], acc);
}

__global__ void router_finish_kernel(const float* __restrict__ hacc, const float* __restrict__ b1,
                                     const float* __restrict__ w2, const float* __restrict__ b2,
                                     int* __restrict__ top, float* __restrict__ bal_out) {
    __shared__ float h_lds[B_][HID_];
    __shared__ float logit[B_][E_];
    __shared__ float probs[B_][E_];
    int t = threadIdx.x; // 128
    for (int b = 0; b < B_; ++b) {
        float v = hacc[b * HID_ + t] + b1[t];
        // jax.nn.gelu default approximate=True (tanh form)
        float u = 0.7978845608028654f * (v + 0.044715f * v * v * v);
        h_lds[b][t] = 0.5f * v * (1.0f + tanhf(u));
    }
    __syncthreads();
    if (t < B_ * E_) {
        int b = t >> 2, e = t & 3;
        float acc = b2[e];
        for (int j = 0; j < HID_; ++j) acc += h_lds[b][j] * w2[j * E_ + e];
        logit[b][e] = acc;
    }
    __syncthreads();
    if (t < B_) {
        int b = t;
        float m = logit[b][0]; int arg = 0;
        for (int e = 1; e < E_; ++e) if (logit[b][e] > m) { m = logit[b][e]; arg = e; } // first-max like jnp.argmax
        float s = 0.f, p[E_];
        for (int e = 0; e < E_; ++e) { p[e] = expf(logit[b][e] - m); s += p[e]; }
        for (int e = 0; e < E_; ++e) probs[b][e] = p[e] / s;
        top[b] = arg;
    }
    __syncthreads();
    if (t == 0) {
        float bal = 0.f;
        for (int e = 0; e < E_; ++e) {
            float avg = 0.25f * (probs[0][e] + probs[1][e] + probs[2][e] + probs[3][e]);
            bal += avg * avg;
        }
        *bal_out = 0.01f * E_ * bal;
    }
}

// xr[b,s,r] = sum_d x[b,s,d] * A[e,r,d]
__global__ __launch_bounds__(256) void xr_kernel(const float* __restrict__ x,
                                                 const float* __restrict__ loraA,
                                                 const int* __restrict__ top,
                                                 float* __restrict__ xr) {
    __shared__ float xs[32][132];
    __shared__ float as[64][132];
    int b = blockIdx.y;
    int e = top[b];
    int s0 = blockIdx.x * 32;
    int rq = threadIdx.x & 31, sq = threadIdx.x >> 5;
    float acc[4][2] = {};
    const float* xb = x + ((size_t)b * S_ + s0) * D_;
    const float* Ab = loraA + (size_t)e * R_ * D_;
    for (int d0 = 0; d0 < D_; d0 += 128) {
#pragma unroll
        for (int i = 0; i < 4; ++i) {
            int lin = threadIdx.x + i * 256; int s = lin >> 5; int dq = lin & 31;
            float4 v = *(const float4*)(xb + (size_t)s * D_ + d0 + dq * 4);
            *(float4*)&xs[s][dq * 4] = v;
        }
#pragma unroll
        for (int i = 0; i < 8; ++i) {
            int lin = threadIdx.x + i * 256; int r = lin >> 5; int dq = lin & 31;
            float4 v = *(const float4*)(Ab + (size_t)r * D_ + d0 + dq * 4);
            *(float4*)&as[r][dq * 4] = v;
        }
        __syncthreads();
#pragma unroll 4
        for (int d4 = 0; d4 < 32; ++d4) {
            float4 xa[4], aa[2];
#pragma unroll
            for (int i = 0; i < 4; ++i) xa[i] = *(const float4*)&xs[sq * 4 + i][d4 * 4];
#pragma unroll
            for (int j = 0; j < 2; ++j) aa[j] = *(const float4*)&as[rq + 32 * j][d4 * 4];
#pragma unroll
            for (int i = 0; i < 4; ++i)
#pragma unroll
                for (int j = 0; j < 2; ++j)
                    acc[i][j] += xa[i].x * aa[j].x + xa[i].y * aa[j].y +
                                 xa[i].z * aa[j].z + xa[i].w * aa[j].w;
        }
        __syncthreads();
    }
#pragma unroll
    for (int i = 0; i < 4; ++i)
#pragma unroll
        for (int j = 0; j < 2; ++j)
            xr[((size_t)b * S_ + s0 + sq * 4 + i) * R_ + rq + 32 * j] = acc[i][j];
}

// out[b,s,o] = 2 * sum_r xr[b,s,r] * Bl[e,o,r]
__global__ __launch_bounds__(256) void out_kernel(const float* __restrict__ xr,
                                                  const float* __restrict__ loraB,
                                                  const int* __restrict__ top,
                                                  float* __restrict__ out) {
    __shared__ float xr_l[32][68];
    __shared__ float bs_t[64][132];   // B tile transposed: [r][o] so inner reads are o-contiguous
    int b = blockIdx.y;
    int e = top[b];
    int s0 = blockIdx.x * 32;
#pragma unroll
    for (int i = 0; i < 2; ++i) {
        int lin = threadIdx.x + i * 256; int s = lin >> 4; int r4 = lin & 15;
        float4 v = *(const float4*)(xr + ((size_t)b * S_ + s0 + s) * R_ + r4 * 4);
        *(float4*)&xr_l[s][r4 * 4] = v;
    }
    int oq = threadIdx.x & 31, sq = threadIdx.x >> 5;
    const float* Bb = loraB + (size_t)e * OUT_ * R_;
    float* ob = out + ((size_t)b * S_ + s0) * OUT_;
    for (int o0 = 0; o0 < OUT_; o0 += 128) {
        __syncthreads();  // protects bs_t reuse; first iter also covers xr_l stores
#pragma unroll
        for (int i = 0; i < 8; ++i) {
            int lin = threadIdx.x + i * 256; int o = lin >> 4; int r4 = lin & 15;
            float4 v = *(const float4*)(Bb + (size_t)(o0 + o) * R_ + r4 * 4);
            bs_t[r4 * 4 + 0][o] = v.x; bs_t[r4 * 4 + 1][o] = v.y;
            bs_t[r4 * 4 + 2][o] = v.z; bs_t[r4 * 4 + 3][o] = v.w;
        }
        __syncthreads();
        float acc[4][4] = {};
#pragma unroll 4
        for (int r4 = 0; r4 < 16; ++r4) {
            float4 xa[4], bb[4];
#pragma unroll
            for (int i = 0; i < 4; ++i) xa[i] = *(const float4*)&xr_l[sq * 4 + i][r4 * 4];
#pragma unroll
            for (int k = 0; k < 4; ++k) bb[k] = *(const float4*)&bs_t[r4 * 4 + k][oq * 4];
#pragma unroll
            for (int i = 0; i < 4; ++i) {
                const float* xv = (const float*)&xa[i];
                acc[i][0] += xv[0] * bb[0].x + xv[1] * bb[1].x + xv[2] * bb[2].x + xv[3] * bb[3].x;
                acc[i][1] += xv[0] * bb[0].y + xv[1] * bb[1].y + xv[2] * bb[2].y + xv[3] * bb[3].y;
                acc[i][2] += xv[0] * bb[0].z + xv[1] * bb[1].z + xv[2] * bb[2].z + xv[3] * bb[3].z;
                acc[i][3] += xv[0] * bb[0].w + xv[1] * bb[1].w + xv[2] * bb[2].w + xv[3] * bb[3].w;
            }
        }
#pragma unroll
        for (int i = 0; i < 4; ++i) {
            float4 v = { acc[i][0] * SCALING_, acc[i][1] * SCALING_,
                         acc[i][2] * SCALING_, acc[i][3] * SCALING_ };
            *(float4*)(ob + (size_t)(sq * 4 + i) * OUT_ + o0 + oq * 4) = v;
        }
    }
}

extern "C" void kernel_launch(void* const* d_in, const int* in_sizes, int n_in,
                              void* d_out, int out_size, void* d_ws, size_t ws_size,
                              hipStream_t stream) {
    const float* x   = (const float*)d_in[0];
    const float* rel = (const float*)d_in[1];
    const float* reg = (const float*)d_in[2];
    const float* lA  = (const float*)d_in[3];
    const float* lB  = (const float*)d_in[4];
    const float* w1  = (const float*)d_in[5];
    const float* b1  = (const float*)d_in[6];
    const float* w2  = (const float*)d_in[7];
    const float* b2  = (const float*)d_in[8];
    float* out = (float*)d_out;
    float* ws  = (float*)d_ws;

    float* pool = ws + WS_POOL;
    float* hacc = ws + WS_HACC;
    int*   top  = (int*)(ws + WS_TOP);
    float* xr   = ws + WS_XR;

    // zero the accumulated regions (ws is poisoned 0xAA and never re-poisoned)
    hipMemsetAsync(ws, 0, (size_t)(B_ * D_ + B_ * HID_) * sizeof(float), stream);

    pool_kernel<<<dim3(16, 16), 256, 0, stream>>>(x, pool);
    router_h_kernel<<<dim3(4, 16), 128, 0, stream>>>(pool, rel, reg, w1, hacc);
    router_finish_kernel<<<1, 128, 0, stream>>>(hacc, b1, w2, b2, top,
                                                out + (size_t)out_size - 1);
    xr_kernel<<<dim3(64, 4), 256, 0, stream>>>(x, lA, top, xr);
    out_kernel<<<dim3(64, 4), 256, 0, stream>>>(xr, lB, top, out);
}

// Round 2
// 197.097 us; speedup vs baseline: 1.9902x; 1.9902x over previous
//
#include <hip/hip_runtime.h>

// MoE-LoRA top-1 dispatch. Router fp32; both LoRA GEMMs on bf16 MFMA (16x16x32).
constexpr int B_ = 4, S_ = 2048, D_ = 4096, E_ = 4, R_ = 64, OUT_ = 4096;
constexpr int NMOD = 4, NREG = 3, HID_ = 128;
constexpr int RIN_ = D_ + NMOD + NREG;      // 4103
constexpr float SCALING_ = 2.0f;            // alpha/rank
constexpr int KSPLIT = 8, KCH = D_ / KSPLIT;// 512

// ws layout (float units)
constexpr size_t WS_POOL = 0;                                   // B*D f32 (sum over S)
constexpr size_t WS_HACC = WS_POOL + B_ * D_;                   // B*HID f32
constexpr size_t WS_TOP  = WS_HACC + B_ * HID_;                 // B ints
constexpr size_t WS_ABF  = WS_TOP + 16;                         // E*R*D bf16 (ushort)
constexpr size_t WS_BBF  = WS_ABF + (size_t)E_ * R_ * D_ / 2;   // E*OUT*R bf16
constexpr size_t WS_XR   = WS_BBF + (size_t)E_ * OUT_ * R_ / 2; // B*S*R f32

using short8 = __attribute__((ext_vector_type(8))) short;
using f32x4  = __attribute__((ext_vector_type(4))) float;

__device__ inline unsigned short f2bf(float f) {  // RNE fp32 -> bf16
    unsigned u = __float_as_uint(f);
    unsigned r = u + 0x7FFFu + ((u >> 16) & 1u);
    return (unsigned short)(r >> 16);
}

__global__ void cvt_w_kernel(const float* __restrict__ A, const float* __restrict__ Bw,
                             ushort* __restrict__ Abf, ushort* __restrict__ Bbf) {
    int i = blockIdx.x * blockDim.x + threadIdx.x;  // float4 id
    constexpr int N4 = E_ * R_ * D_ / 4;            // 262144 per tensor
    if (i < N4) {
        float4 v = ((const float4*)A)[i];
        ushort4 o = make_ushort4(f2bf(v.x), f2bf(v.y), f2bf(v.z), f2bf(v.w));
        ((ushort4*)Abf)[i] = o;
    } else {
        int j = i - N4;
        float4 v = ((const float4*)Bw)[j];
        ushort4 o = make_ushort4(f2bf(v.x), f2bf(v.y), f2bf(v.z), f2bf(v.w));
        ((ushort4*)Bbf)[j] = o;
    }
}

__global__ void pool_kernel(const float* __restrict__ x, float* __restrict__ pool) {
    int q  = blockIdx.x * blockDim.x + threadIdx.x;   // float4 col id, 0..B*D/4
    int b  = q >> 10;                                  // D/4 = 1024
    int dq = q & 1023;
    int s0 = blockIdx.y * 32;                          // 64 y-blocks x 32 rows
    const float4* xp = (const float4*)x + (size_t)b * S_ * 1024 + (size_t)s0 * 1024 + dq;
    float4 acc = {0.f, 0.f, 0.f, 0.f};
    for (int s = 0; s < 32; ++s) {
        float4 v = xp[(size_t)s * 1024];
        acc.x += v.x; acc.y += v.y; acc.z += v.z; acc.w += v.w;
    }
    float* p = pool + b * D_ + dq * 4;
    atomicAdd(p + 0, acc.x); atomicAdd(p + 1, acc.y);
    atomicAdd(p + 2, acc.z); atomicAdd(p + 3, acc.w);
}

__global__ void router_h_kernel(const float* __restrict__ pool, const float* __restrict__ rel,
                                const float* __restrict__ reg, const float* __restrict__ w1,
                                float* __restrict__ hacc) {
    int b = blockIdx.x, kc = blockIdx.y, h = threadIdx.x; // 128 threads
    int k0 = kc * 257;
    int k1 = k0 + 257 < RIN_ ? k0 + 257 : RIN_;
    float acc = 0.f;
    for (int k = k0; k < k1; ++k) {
        float rin;
        if (k < D_)             rin = pool[b * D_ + k] * (1.0f / S_);
        else if (k < D_ + NMOD) rin = rel[b * NMOD + (k - D_)];
        else                    rin = reg[b * NREG + (k - D_ - NMOD)];
        acc += rin * w1[k * HID_ + h];
    }
    atomicAdd(&hacc[b * HID_ + h], acc);
}

__global__ void router_finish_kernel(const float* __restrict__ hacc, const float* __restrict__ b1,
                                     const float* __restrict__ w2, const float* __restrict__ b2,
                                     int* __restrict__ top, float* __restrict__ bal_out) {
    __shared__ float h_lds[B_][HID_];
    __shared__ float logit[B_][E_];
    __shared__ float probs[B_][E_];
    int t = threadIdx.x; // 128
    for (int b = 0; b < B_; ++b) {
        float v = hacc[b * HID_ + t] + b1[t];
        float u = 0.7978845608028654f * (v + 0.044715f * v * v * v); // tanh-GELU
        h_lds[b][t] = 0.5f * v * (1.0f + tanhf(u));
    }
    __syncthreads();
    if (t < B_ * E_) {
        int b = t >> 2, e = t & 3;
        float acc = b2[e];
        for (int j = 0; j < HID_; ++j) acc += h_lds[b][j] * w2[j * E_ + e];
        logit[b][e] = acc;
    }
    __syncthreads();
    if (t < B_) {
        int b = t;
        float m = logit[b][0]; int arg = 0;
        for (int e = 1; e < E_; ++e) if (logit[b][e] > m) { m = logit[b][e]; arg = e; }
        float s = 0.f, p[E_];
        for (int e = 0; e < E_; ++e) { p[e] = expf(logit[b][e] - m); s += p[e]; }
        for (int e = 0; e < E_; ++e) probs[b][e] = p[e] / s;
        top[b] = arg;
    }
    __syncthreads();
    if (t == 0) {
        float bal = 0.f;
        for (int e = 0; e < E_; ++e) {
            float avg = 0.25f * (probs[0][e] + probs[1][e] + probs[2][e] + probs[3][e]);
            bal += avg * avg;
        }
        *bal_out = 0.01f * E_ * bal;
    }
}

// xr[b,s,r] += sum_{k in block's K-slice} x[b,s,k] * A_bf[e,r,k]   (K-split x8, atomic f32)
__global__ __launch_bounds__(256) void xr_kernel(const float* __restrict__ x,
                                                 const ushort* __restrict__ Abf,
                                                 const int* __restrict__ top,
                                                 float* __restrict__ xr) {
    __shared__ ushort xs[64][72];   // 144B row stride = 9x16B -> conflict-minimal b128
    __shared__ ushort as[64][72];
    int b  = blockIdx.y;
    int e  = top[b];
    int s0 = blockIdx.x * 64;
    int kz = blockIdx.z * KCH;
    int t = threadIdx.x, lane = t & 63, w = t >> 6;
    const float*  xb = x   + ((size_t)b * S_ + s0) * D_;
    const ushort* Ab = Abf + (size_t)e * R_ * D_;
    f32x4 acc[4] = {};
    for (int k0 = kz; k0 < kz + KCH; k0 += 64) {
#pragma unroll
        for (int i = 0; i < 4; ++i) {               // stage x 64x64 f32 -> bf16
            int lin = t + 256 * i; int row = lin >> 4, fq = lin & 15;
            float4 v = *(const float4*)(xb + (size_t)row * D_ + k0 + fq * 4);
            ushort4 o = make_ushort4(f2bf(v.x), f2bf(v.y), f2bf(v.z), f2bf(v.w));
            *(ushort4*)&xs[row][fq * 4] = o;
        }
#pragma unroll
        for (int i = 0; i < 2; ++i) {               // stage A 64x64 bf16
            int lin = t + 256 * i; int row = lin >> 3, cq = lin & 7;
            int4 v = *(const int4*)(Ab + (size_t)row * D_ + k0 + cq * 8);
            *(int4*)&as[row][cq * 8] = v;
        }
        __syncthreads();
        int mrow = w * 16 + (lane & 15);
        int koff = (lane >> 4) * 8;
#pragma unroll
        for (int kk = 0; kk < 2; ++kk) {
            short8 af = *(const short8*)&xs[mrow][kk * 32 + koff];
#pragma unroll
            for (int n = 0; n < 4; ++n) {
                short8 bf = *(const short8*)&as[n * 16 + (lane & 15)][kk * 32 + koff];
                acc[n] = __builtin_amdgcn_mfma_f32_16x16x32_bf16(af, bf, acc[n], 0, 0, 0);
            }
        }
        __syncthreads();
    }
    // C/D: col = lane&15 (within 16-col frag), row = (lane>>4)*4 + i
    int col0  = lane & 15;
    int rbase = w * 16 + ((lane >> 4) << 2);
#pragma unroll
    for (int n = 0; n < 4; ++n)
#pragma unroll
        for (int i = 0; i < 4; ++i)
            atomicAdd(&xr[((size_t)b * S_ + s0 + rbase + i) * R_ + n * 16 + col0], acc[n][i]);
}

// out[b,s,o] = 2 * sum_r xr[b,s,r] * B_bf[e,o,r]
__global__ __launch_bounds__(256) void out_kernel(const float* __restrict__ xr,
                                                  const ushort* __restrict__ Bbf,
                                                  const int* __restrict__ top,
                                                  float* __restrict__ out) {
    __shared__ ushort xrs[64][72];
    __shared__ ushort bs[128][72];
    int b  = blockIdx.z;
    int e  = top[b];
    int s0 = blockIdx.x * 64, o0 = blockIdx.y * 128;
    int t = threadIdx.x, lane = t & 63, w = t >> 6;
#pragma unroll
    for (int i = 0; i < 4; ++i) {                   // stage xr 64x64 f32 -> bf16
        int lin = t + 256 * i; int row = lin >> 4, fq = lin & 15;
        float4 v = *(const float4*)(xr + ((size_t)b * S_ + s0 + row) * R_ + fq * 4);
        ushort4 o = make_ushort4(f2bf(v.x), f2bf(v.y), f2bf(v.z), f2bf(v.w));
        *(ushort4*)&xrs[row][fq * 4] = o;
    }
    const ushort* Bb = Bbf + (size_t)e * OUT_ * R_ + (size_t)o0 * R_;
#pragma unroll
    for (int i = 0; i < 4; ++i) {                   // stage B 128x64 bf16 (contiguous)
        int lin = t + 256 * i; int row = lin >> 3, cq = lin & 7;
        int4 v = *(const int4*)(Bb + (size_t)row * R_ + cq * 8);
        *(int4*)&bs[row][cq * 8] = v;
    }
    __syncthreads();
    int mrow = w * 16 + (lane & 15);
    int koff = (lane >> 4) * 8;
    f32x4 acc[8] = {};
#pragma unroll
    for (int kk = 0; kk < 2; ++kk) {
        short8 af = *(const short8*)&xrs[mrow][kk * 32 + koff];
#pragma unroll
        for (int n = 0; n < 8; ++n) {
            short8 bf = *(const short8*)&bs[n * 16 + (lane & 15)][kk * 32 + koff];
            acc[n] = __builtin_amdgcn_mfma_f32_16x16x32_bf16(af, bf, acc[n], 0, 0, 0);
        }
    }
    int col0  = lane & 15;
    int rbase = (lane >> 4) << 2;
    float* ob = out + ((size_t)b * S_ + s0 + w * 16) * OUT_ + o0;
#pragma unroll
    for (int n = 0; n < 8; ++n)
#pragma unroll
        for (int i = 0; i < 4; ++i)
            ob[(size_t)(rbase + i) * OUT_ + n * 16 + col0] = acc[n][i] * SCALING_;
}

extern "C" void kernel_launch(void* const* d_in, const int* in_sizes, int n_in,
                              void* d_out, int out_size, void* d_ws, size_t ws_size,
                              hipStream_t stream) {
    const float* x   = (const float*)d_in[0];
    const float* rel = (const float*)d_in[1];
    const float* reg = (const float*)d_in[2];
    const float* lA  = (const float*)d_in[3];
    const float* lB  = (const float*)d_in[4];
    const float* w1  = (const float*)d_in[5];
    const float* b1  = (const float*)d_in[6];
    const float* w2  = (const float*)d_in[7];
    const float* b2  = (const float*)d_in[8];
    float* out = (float*)d_out;
    float* ws  = (float*)d_ws;

    float*  pool = ws + WS_POOL;
    float*  hacc = ws + WS_HACC;
    int*    top  = (int*)(ws + WS_TOP);
    ushort* Abf  = (ushort*)(ws + WS_ABF);
    ushort* Bbf  = (ushort*)(ws + WS_BBF);
    float*  xr   = ws + WS_XR;

    // zero accumulated regions (ws poisoned 0xAA, never re-poisoned)
    hipMemsetAsync(ws, 0, (size_t)(B_ * D_ + B_ * HID_) * sizeof(float), stream);
    hipMemsetAsync(xr, 0, (size_t)B_ * S_ * R_ * sizeof(float), stream);

    cvt_w_kernel<<<2 * (E_ * R_ * D_ / 4) / 256, 256, 0, stream>>>(lA, lB, Abf, Bbf);
    pool_kernel<<<dim3(B_ * D_ / 4 / 256, 64), 256, 0, stream>>>(x, pool);
    router_h_kernel<<<dim3(4, 16), 128, 0, stream>>>(pool, rel, reg, w1, hacc);
    router_finish_kernel<<<1, 128, 0, stream>>>(hacc, b1, w2, b2, top,
                                                out + (size_t)out_size - 1);
    xr_kernel<<<dim3(S_ / 64, B_, KSPLIT), 256, 0, stream>>>(x, Abf, top, xr);
    out_kernel<<<dim3(S_ / 64, OUT_ / 128, B_), 256, 0, stream>>>(xr, Bbf, top, out);
}

// Round 3
// 150.918 us; speedup vs baseline: 2.5991x; 1.3060x over previous
//
#include <hip/hip_runtime.h>

// MoE-LoRA top-1 dispatch. Router fp32; both LoRA GEMMs on bf16 MFMA (16x16x32).
constexpr int B_ = 4, S_ = 2048, D_ = 4096, E_ = 4, R_ = 64, OUT_ = 4096;
constexpr int NMOD = 4, NREG = 3, HID_ = 128;
constexpr int RIN_ = D_ + NMOD + NREG;      // 4103
constexpr float SCALING_ = 2.0f;            // alpha/rank
constexpr int KSPLIT = 8, KCH = D_ / KSPLIT;// 512
constexpr int KC_ = 33;                     // router k-chunks of 128 rows (33*128 >= 4103)

// ws layout (float units)
constexpr size_t WS_POOL  = 0;                                    // B*D f32 (sum over S)
constexpr size_t WS_HACC2 = WS_POOL + B_ * D_;                    // B*KC_*HID f32 partials
constexpr size_t WS_TOP   = WS_HACC2 + B_ * KC_ * HID_;           // B ints
constexpr size_t WS_ABF   = WS_TOP + 16;                          // E*R*D bf16 (ushort)
constexpr size_t WS_BBF   = WS_ABF + (size_t)E_ * R_ * D_ / 2;    // E*OUT*R bf16
constexpr size_t WS_XR    = WS_BBF + (size_t)E_ * OUT_ * R_ / 2;  // B*S*R f32

using short8 = __attribute__((ext_vector_type(8))) short;
using f32x4  = __attribute__((ext_vector_type(4))) float;

__device__ inline unsigned short f2bf(float f) {  // RNE fp32 -> bf16
    unsigned u = __float_as_uint(f);
    unsigned r = u + 0x7FFFu + ((u >> 16) & 1u);
    return (unsigned short)(r >> 16);
}

__global__ void cvt_w_kernel(const float* __restrict__ A, const float* __restrict__ Bw,
                             ushort* __restrict__ Abf, ushort* __restrict__ Bbf) {
    int i = blockIdx.x * blockDim.x + threadIdx.x;  // float4 id
    constexpr int N4 = E_ * R_ * D_ / 4;            // 262144 per tensor
    if (i < N4) {
        float4 v = ((const float4*)A)[i];
        ushort4 o = make_ushort4(f2bf(v.x), f2bf(v.y), f2bf(v.z), f2bf(v.w));
        ((ushort4*)Abf)[i] = o;
    } else {
        int j = i - N4;
        float4 v = ((const float4*)Bw)[j];
        ushort4 o = make_ushort4(f2bf(v.x), f2bf(v.y), f2bf(v.z), f2bf(v.w));
        ((ushort4*)Bbf)[j] = o;
    }
}

__global__ void pool_kernel(const float* __restrict__ x, float* __restrict__ pool) {
    int q  = blockIdx.x * blockDim.x + threadIdx.x;   // float4 col id, 0..B*D/4
    int b  = q >> 10;                                  // D/4 = 1024
    int dq = q & 1023;
    int s0 = blockIdx.y * 32;                          // 64 y-blocks x 32 rows
    const float4* xp = (const float4*)x + (size_t)b * S_ * 1024 + (size_t)s0 * 1024 + dq;
    float4 acc = {0.f, 0.f, 0.f, 0.f};
    for (int s = 0; s < 32; ++s) {
        float4 v = xp[(size_t)s * 1024];
        acc.x += v.x; acc.y += v.y; acc.z += v.z; acc.w += v.w;
    }
    float* p = pool + b * D_ + dq * 4;
    atomicAdd(p + 0, acc.x); atomicAdd(p + 1, acc.y);
    atomicAdd(p + 2, acc.z); atomicAdd(p + 3, acc.w);
}

// hacc2[b][kc][h] = sum over this chunk's 128 k-rows of router_in[k]*w1[k][h]
__global__ __launch_bounds__(256) void router_h_kernel(const float* __restrict__ pool,
                                                       const float* __restrict__ rel,
                                                       const float* __restrict__ reg,
                                                       const float* __restrict__ w1,
                                                       float* __restrict__ hacc2) {
    __shared__ float red[256];
    int b = blockIdx.x, kc = blockIdx.y;
    int t = threadIdx.x;
    int h = t & 127, half = t >> 7;
    int k0 = kc * 128;
    float acc = 0.f;
#pragma unroll 8
    for (int i = 0; i < 64; ++i) {
        int k = k0 + 2 * i + half;
        if (k < RIN_) {
            float rin;
            if (k < D_)             rin = pool[b * D_ + k] * (1.0f / S_);
            else if (k < D_ + NMOD) rin = rel[b * NMOD + (k - D_)];
            else                    rin = reg[b * NREG + (k - D_ - NMOD)];
            acc += rin * w1[(size_t)k * HID_ + h];
        }
    }
    red[t] = acc;
    __syncthreads();
    if (t < 128)
        hacc2[((size_t)b * KC_ + kc) * HID_ + t] = red[t] + red[t + 128];
}

__global__ void router_finish_kernel(const float* __restrict__ hacc2, const float* __restrict__ b1,
                                     const float* __restrict__ w2, const float* __restrict__ b2,
                                     int* __restrict__ top, float* __restrict__ bal_out) {
    __shared__ float h_lds[B_][HID_];
    __shared__ float logit[B_][E_];
    __shared__ float probs[B_][E_];
    int t = threadIdx.x; // 128
    for (int b = 0; b < B_; ++b) {
        float v = b1[t];
        for (int j = 0; j < KC_; ++j) v += hacc2[((size_t)b * KC_ + j) * HID_ + t];
        float u = 0.7978845608028654f * (v + 0.044715f * v * v * v); // tanh-GELU
        h_lds[b][t] = 0.5f * v * (1.0f + tanhf(u));
    }
    __syncthreads();
    if (t < B_ * E_) {
        int b = t >> 2, e = t & 3;
        float acc = b2[e];
        for (int j = 0; j < HID_; ++j) acc += h_lds[b][j] * w2[j * E_ + e];
        logit[b][e] = acc;
    }
    __syncthreads();
    if (t < B_) {
        int b = t;
        float m = logit[b][0]; int arg = 0;
        for (int e = 1; e < E_; ++e) if (logit[b][e] > m) { m = logit[b][e]; arg = e; }
        float s = 0.f, p[E_];
        for (int e = 0; e < E_; ++e) { p[e] = expf(logit[b][e] - m); s += p[e]; }
        for (int e = 0; e < E_; ++e) probs[b][e] = p[e] / s;
        top[b] = arg;
    }
    __syncthreads();
    if (t == 0) {
        float bal = 0.f;
        for (int e = 0; e < E_; ++e) {
            float avg = 0.25f * (probs[0][e] + probs[1][e] + probs[2][e] + probs[3][e]);
            bal += avg * avg;
        }
        *bal_out = 0.01f * E_ * bal;
    }
}

// xr[b,s,r] += sum_{k in block's K-slice} x[b,s,k] * A_bf[e,r,k]   (K-split x8, atomic f32)
__global__ __launch_bounds__(256) void xr_kernel(const float* __restrict__ x,
                                                 const ushort* __restrict__ Abf,
                                                 const int* __restrict__ top,
                                                 float* __restrict__ xr) {
    __shared__ ushort xs[64][72];   // 144B row stride = 9x16B -> conflict-minimal b128
    __shared__ ushort as[64][72];
    int b  = blockIdx.y;
    int e  = top[b];
    int s0 = blockIdx.x * 64;
    int kz = blockIdx.z * KCH;
    int t = threadIdx.x, lane = t & 63, w = t >> 6;
    const float*  xb = x   + ((size_t)b * S_ + s0) * D_;
    const ushort* Ab = Abf + (size_t)e * R_ * D_;
    f32x4 acc[4] = {};
    for (int k0 = kz; k0 < kz + KCH; k0 += 64) {
#pragma unroll
        for (int i = 0; i < 4; ++i) {               // stage x 64x64 f32 -> bf16
            int lin = t + 256 * i; int row = lin >> 4, fq = lin & 15;
            float4 v = *(const float4*)(xb + (size_t)row * D_ + k0 + fq * 4);
            ushort4 o = make_ushort4(f2bf(v.x), f2bf(v.y), f2bf(v.z), f2bf(v.w));
            *(ushort4*)&xs[row][fq * 4] = o;
        }
#pragma unroll
        for (int i = 0; i < 2; ++i) {               // stage A 64x64 bf16
            int lin = t + 256 * i; int row = lin >> 3, cq = lin & 7;
            int4 v = *(const int4*)(Ab + (size_t)row * D_ + k0 + cq * 8);
            *(int4*)&as[row][cq * 8] = v;
        }
        __syncthreads();
        int mrow = w * 16 + (lane & 15);
        int koff = (lane >> 4) * 8;
#pragma unroll
        for (int kk = 0; kk < 2; ++kk) {
            short8 af = *(const short8*)&xs[mrow][kk * 32 + koff];
#pragma unroll
            for (int n = 0; n < 4; ++n) {
                short8 bf = *(const short8*)&as[n * 16 + (lane & 15)][kk * 32 + koff];
                acc[n] = __builtin_amdgcn_mfma_f32_16x16x32_bf16(af, bf, acc[n], 0, 0, 0);
            }
        }
        __syncthreads();
    }
    // C/D: col = lane&15, row = (lane>>4)*4 + i
    int col0  = lane & 15;
    int rbase = w * 16 + ((lane >> 4) << 2);
#pragma unroll
    for (int n = 0; n < 4; ++n)
#pragma unroll
        for (int i = 0; i < 4; ++i)
            atomicAdd(&xr[((size_t)b * S_ + s0 + rbase + i) * R_ + n * 16 + col0], acc[n][i]);
}

// out[b,s,o] = 2 * sum_r xr[b,s,r] * B_bf[e,o,r]
__global__ __launch_bounds__(256) void out_kernel(const float* __restrict__ xr,
                                                  const ushort* __restrict__ Bbf,
                                                  const int* __restrict__ top,
                                                  float* __restrict__ out) {
    __shared__ ushort xrs[64][72];
    __shared__ ushort bs[128][72];
    int b  = blockIdx.z;
    int e  = top[b];
    int s0 = blockIdx.x * 64, o0 = blockIdx.y * 128;
    int t = threadIdx.x, lane = t & 63, w = t >> 6;
#pragma unroll
    for (int i = 0; i < 4; ++i) {                   // stage xr 64x64 f32 -> bf16
        int lin = t + 256 * i; int row = lin >> 4, fq = lin & 15;
        float4 v = *(const float4*)(xr + ((size_t)b * S_ + s0 + row) * R_ + fq * 4);
        ushort4 o = make_ushort4(f2bf(v.x), f2bf(v.y), f2bf(v.z), f2bf(v.w));
        *(ushort4*)&xrs[row][fq * 4] = o;
    }
    const ushort* Bb = Bbf + (size_t)e * OUT_ * R_ + (size_t)o0 * R_;
#pragma unroll
    for (int i = 0; i < 4; ++i) {                   // stage B 128x64 bf16 (contiguous)
        int lin = t + 256 * i; int row = lin >> 3, cq = lin & 7;
        int4 v = *(const int4*)(Bb + (size_t)row * R_ + cq * 8);
        *(int4*)&bs[row][cq * 8] = v;
    }
    __syncthreads();
    int mrow = w * 16 + (lane & 15);
    int koff = (lane >> 4) * 8;
    f32x4 acc[8] = {};
#pragma unroll
    for (int kk = 0; kk < 2; ++kk) {
        short8 af = *(const short8*)&xrs[mrow][kk * 32 + koff];
#pragma unroll
        for (int n = 0; n < 8; ++n) {
            short8 bf = *(const short8*)&bs[n * 16 + (lane & 15)][kk * 32 + koff];
            acc[n] = __builtin_amdgcn_mfma_f32_16x16x32_bf16(af, bf, acc[n], 0, 0, 0);
        }
    }
    int col0  = lane & 15;
    int rbase = (lane >> 4) << 2;
    float* ob = out + ((size_t)b * S_ + s0 + w * 16) * OUT_ + o0;
#pragma unroll
    for (int n = 0; n < 8; ++n)
#pragma unroll
        for (int i = 0; i < 4; ++i)
            ob[(size_t)(rbase + i) * OUT_ + n * 16 + col0] = acc[n][i] * SCALING_;
}

extern "C" void kernel_launch(void* const* d_in, const int* in_sizes, int n_in,
                              void* d_out, int out_size, void* d_ws, size_t ws_size,
                              hipStream_t stream) {
    const float* x   = (const float*)d_in[0];
    const float* rel = (const float*)d_in[1];
    const float* reg = (const float*)d_in[2];
    const float* lA  = (const float*)d_in[3];
    const float* lB  = (const float*)d_in[4];
    const float* w1  = (const float*)d_in[5];
    const float* b1  = (const float*)d_in[6];
    const float* w2  = (const float*)d_in[7];
    const float* b2  = (const float*)d_in[8];
    float* out = (float*)d_out;
    float* ws  = (float*)d_ws;

    float*  pool  = ws + WS_POOL;
    float*  hacc2 = ws + WS_HACC2;
    int*    top   = (int*)(ws + WS_TOP);
    ushort* Abf   = (ushort*)(ws + WS_ABF);
    ushort* Bbf   = (ushort*)(ws + WS_BBF);
    float*  xr    = ws + WS_XR;

    // zero accumulated regions (ws poisoned 0xAA, never re-poisoned)
    hipMemsetAsync(pool, 0, (size_t)B_ * D_ * sizeof(float), stream);
    hipMemsetAsync(xr, 0, (size_t)B_ * S_ * R_ * sizeof(float), stream);

    cvt_w_kernel<<<2 * (E_ * R_ * D_ / 4) / 256, 256, 0, stream>>>(lA, lB, Abf, Bbf);
    pool_kernel<<<dim3(B_ * D_ / 4 / 256, 64), 256, 0, stream>>>(x, pool);
    router_h_kernel<<<dim3(B_, KC_), 256, 0, stream>>>(pool, rel, reg, w1, hacc2);
    router_finish_kernel<<<1, 128, 0, stream>>>(hacc2, b1, w2, b2, top,
                                                out + (size_t)out_size - 1);
    xr_kernel<<<dim3(S_ / 64, B_, KSPLIT), 256, 0, stream>>>(x, Abf, top, xr);
    out_kernel<<<dim3(S_ / 64, OUT_ / 128, B_), 256, 0, stream>>>(xr, Bbf, top, out);
}